// Round 6
// baseline (512.132 us; speedup 1.0000x reference)
//
#include <hip/hip_runtime.h>

// ---------------------------------------------------------------------------
// CConv: out[n,o] = sum_{m,s,i} sel[n,m,s] * W[s,o,i] * feat[idx[n,m], i]
// Prep:   fused kernel: feat->bf16 AND W->Wt bf16 (k-contiguous), one launch.
// Phase 1: t[n,s,i] = sum_m sel*pf per-n via 32x32x16 MFMA (R5 version:
//          full tbuf, contiguous full-row T store; 167us full-N, 46% HBM).
// Phase 2: out = T x Wt^T, 16x16x32 bf16, BK=64, 64x128 tile, 3-buffer
//          single-barrier counted-vmcnt (R4 schedule, proven correct) at
//          72KB LDS -> 2 blocks/CU (R4's 96KB -> 1 blk/CU was the regression:
//          Occ 8.8%). Session accounting: 2-buf@2blk/CU ~113us, 1-buf@3blk
//          ~137us, 3-buf@1blk 186us -> pipeline + >=2 blk/CU wins.
// R6: chunk N at NC=25088 -> T-chunk 173MB fits 256MB L3: phase2 T-reads
//     become L3 hits (latency ~3x down), T HBM round-trip mostly vanishes.
// ---------------------------------------------------------------------------

#define N_CHI 128
#define N_SP  27
#define N_M   32
#define KDIM  (N_SP * N_CHI)      // 3456
#define SEL_STRIDE (N_M * N_SP)   // 864

typedef short s16x8 __attribute__((ext_vector_type(8)));
typedef s16x8 __attribute__((may_alias)) s16x8_a;
typedef unsigned short u16x8 __attribute__((ext_vector_type(8)));
typedef u16x8 __attribute__((may_alias)) u16x8_a;
typedef unsigned int u32x2 __attribute__((ext_vector_type(2)));
typedef u32x2 __attribute__((may_alias)) u32x2_a;
typedef float f32x4 __attribute__((ext_vector_type(4)));
typedef f32x4 __attribute__((may_alias)) f32x4_a;
typedef float f32x16 __attribute__((ext_vector_type(16)));

typedef __attribute__((address_space(3))) unsigned int as3_u32;
typedef __attribute__((address_space(1))) const unsigned int as1_u32;

static __device__ __forceinline__ unsigned short f2bf(float f) {
  unsigned int u = __float_as_uint(f);
  u += 0x7FFFu + ((u >> 16) & 1u);   // round-to-nearest-even (inputs finite)
  return (unsigned short)(u >> 16);
}

// --------------------------------------------------------------------------
// Prep (fused): blocks [0, FB_BLKS): feat fp32 -> bf16 (4 elems/thread).
//               blocks [FB_BLKS, FB_BLKS+WT_BLKS): W -> Wt bf16 transpose.
// --------------------------------------------------------------------------
__global__ __launch_bounds__(256) void prep_kernel(
    const float* __restrict__ feat, unsigned short* __restrict__ fb, int total4,
    const float* __restrict__ w, unsigned short* __restrict__ Wt, int fb_blks) {
  const int b = (int)blockIdx.x;
  if (b < fb_blks) {
    const int i = b * 256 + (int)threadIdx.x;
    if (i >= total4) return;
    f32x4 v = *(const f32x4_a*)&feat[(size_t)i * 4];
    u32x2 o;
    o[0] = (unsigned int)f2bf(v[0]) | ((unsigned int)f2bf(v[1]) << 16);
    o[1] = (unsigned int)f2bf(v[2]) | ((unsigned int)f2bf(v[3]) << 16);
    *(u32x2_a*)&fb[(size_t)i * 4] = o;
  } else {
    // e enumerates (s*128+o)*128+i linearly -> coalesced read of w
    const int e = (b - fb_blks) * 256 + (int)threadIdx.x;   // < 27*128*128
    const int i = e & 127;
    const int so = e >> 7;
    const int o = so & 127;
    const int s = so >> 7;
    Wt[((size_t)o * N_SP + s) * N_CHI + i] = f2bf(w[e]);
  }
}

// --------------------------------------------------------------------------
// Kernel 1: per-n  t^T[i][s] = pf^T(128x32m) x sel(32m x 32s)  via 32x32x16.
// acc -> per-wave LDS tbuf (8B-granule XOR swizzle) -> 7 coalesced b128
// stores of the FULL contiguous T row (no write amplification).
// --------------------------------------------------------------------------
__global__ __launch_bounds__(256, 5) void phase1_kernel(
    const unsigned short* __restrict__ featbf, const float* __restrict__ sel,
    const int* __restrict__ nidx, unsigned short* __restrict__ T,
    int nbase, int nend) {
  __shared__ __align__(16) unsigned short tbuf[4][N_SP * 128]; // 27648 B
  const int wave = threadIdx.x >> 6;
  const int lane = threadIdx.x & 63;
  const int n = nbase + (int)blockIdx.x * 4 + wave;
  if (n >= nend) return;                 // wave-private LDS: no barriers needed
  unsigned short* tb = tbuf[wave];
  const int q = lane >> 5;     // 0..1  (K-half)
  const int col = lane & 31;   // A-row (i_local) == B-col (s)
  const bool sv = (col < N_SP);

  // B fragments: direct coalesced loads (no LDS staging)
  const float* selp = sel + (size_t)n * SEL_STRIDE;
  s16x8 bf0, bf1;
#pragma unroll
  for (int j = 0; j < 8; ++j) {
    const int m0 = q * 8 + j;
    float v0 = sv ? selp[m0 * N_SP + col] : 0.0f;
    float v1 = sv ? selp[(16 + m0) * N_SP + col] : 0.0f;
    bf0[j] = (short)f2bf(v0);
    bf1[j] = (short)f2bf(v1);
  }

  // neighbor element offsets for this lane's k positions: m = ks*16 + q*8 + j
  const int* ip = nidx + (size_t)n * N_M;
  int offe[16];
#pragma unroll
  for (int ks = 0; ks < 2; ++ks)
#pragma unroll
    for (int j = 0; j < 8; ++j)
      offe[ks * 8 + j] = ip[ks * 16 + q * 8 + j] * N_CHI;

#pragma unroll
  for (int ti = 0; ti < 4; ++ti) {
    const int icol = ti * 32 + col;
    s16x8 af0, af1;
#pragma unroll
    for (int j = 0; j < 8; ++j) {
      af0[j] = (short)featbf[offe[j] + icol];
      af1[j] = (short)featbf[offe[8 + j] + icol];
    }
    f32x16 acc = {0.f, 0.f, 0.f, 0.f, 0.f, 0.f, 0.f, 0.f,
                  0.f, 0.f, 0.f, 0.f, 0.f, 0.f, 0.f, 0.f};
    acc = __builtin_amdgcn_mfma_f32_32x32x16_bf16(af0, bf0, acc, 0, 0, 0);
    acc = __builtin_amdgcn_mfma_f32_32x32x16_bf16(af1, bf1, acc, 0, 0, 0);
    if (sv) {  // s = col; drop padding rows
#pragma unroll
      for (int g = 0; g < 4; ++g) {  // i = ti*32 + q*4 + g*8 + {0..3}
        const int sub = ti * 8 + g * 2 + q;                 // logical granule 0..31
        const int phys = col * 128 + (((sub ^ ((col & 7) << 2))) << 2);
        u32x2 pk;
        pk[0] = (unsigned int)f2bf(acc[4 * g + 0]) | ((unsigned int)f2bf(acc[4 * g + 1]) << 16);
        pk[1] = (unsigned int)f2bf(acc[4 * g + 2]) | ((unsigned int)f2bf(acc[4 * g + 3]) << 16);
        *(u32x2_a*)&tb[phys] = pk;
      }
    }
  }

  // coalesced store: 432 granule-pairs (16B each), 7 wave-iters, CONTIGUOUS row
  unsigned short* Tn = T + (size_t)(n - nbase) * KDIM;
#pragma unroll
  for (int it = 0; it < 7; ++it) {
    const int P = it * 64 + lane;      // pair id, 0..431
    if (P < 432) {
      const int c = P >> 4;            // col (s), 0..26
      const int sub = (P << 1) & 31;   // even logical granule
      const int phys = c * 128 + (((sub ^ ((c & 7) << 2))) << 2);  // 16B aligned
      *(u16x8_a*)&Tn[(size_t)P * 8] = *(const u16x8_a*)&tb[phys];
    }
  }
}

// --------------------------------------------------------------------------
// Kernel 2: out[64n x 128o] = T[64 x 3456] x Wt^T, 16x16x32 bf16, BK=64.
// global_load_lds staging, global-side XOR swizzle (LDS dest must be linear);
// frag ds_read_b128 conflict-free: phys 16B-block bp holds bg = bp ^ (row&7).
// 3-buffer rotation, ONE barrier/kt, counted vmcnt, stage before compute:
//   iter kt: vmcnt(6) [tile kt in, kt+1 flying] -> s_barrier [proves
//   compute(kt-1) done by all -> buf[(kt-1)%3] free] -> stage(kt+2) ->
//   compute(kt).  LDS 72KB -> 2 blocks/CU (avoid R4's 1-blk/CU cliff).
// 4 waves: wave (wm=w&1: 32 rows, wn=w>>1: 64 cols) -> acc 2x4 C-tiles.
// --------------------------------------------------------------------------
__global__ __launch_bounds__(256) void phase2_kernel(
    const unsigned short* __restrict__ T, const unsigned short* __restrict__ Wt,
    float* __restrict__ out, int nbase, int N) {
  __shared__ __align__(16) unsigned short Alds[3][64 * 64];    // 24 KB
  __shared__ __align__(16) unsigned short Blds[3][128 * 64];   // 48 KB
  const int tid = threadIdx.x;
  const int lane = tid & 63;
  const int wbase = tid & ~63;          // wave*64 (uniform per wave)
  const int wave = tid >> 6;
  const int wm = wave & 1, wn = wave >> 1;
  const int quad = lane >> 4, l16 = lane & 15;
  const size_t rowbase = (size_t)blockIdx.x * 64;

  f32x4 acc[2][4];
#pragma unroll
  for (int a = 0; a < 2; ++a)
#pragma unroll
    for (int b = 0; b < 4; ++b) acc[a][b] = (f32x4){0.f, 0.f, 0.f, 0.f};

  // per-thread staging source addresses (slot = it*256 + tid -> row, 16B-block)
  const unsigned short* aga[2];   // A: 64 rows x 8 blocks = 512 slots
  const unsigned short* bga[4];   // B: 128 rows x 8 blocks = 1024 slots
#pragma unroll
  for (int it = 0; it < 2; ++it) {
    const int slot = it * 256 + tid;
    const int r = slot >> 3, bp = slot & 7;
    aga[it] = T + (rowbase + r) * KDIM + ((bp ^ (r & 7)) << 3);
  }
#pragma unroll
  for (int it = 0; it < 4; ++it) {
    const int slot = it * 256 + tid;
    const int r = slot >> 3, bp = slot & 7;
    bga[it] = Wt + (size_t)r * KDIM + ((bp ^ (r & 7)) << 3);
  }

  auto stage = [&](int buf, int k0) {
#pragma unroll
    for (int it = 0; it < 2; ++it)
      __builtin_amdgcn_global_load_lds(
          (as1_u32*)(const void*)(aga[it] + k0),
          (as3_u32*)(void*)&Alds[buf][(it * 256 + wbase) * 8], 16, 0, 0);
#pragma unroll
    for (int it = 0; it < 4; ++it)
      __builtin_amdgcn_global_load_lds(
          (as1_u32*)(const void*)(bga[it] + k0),
          (as3_u32*)(void*)&Blds[buf][(it * 256 + wbase) * 8], 16, 0, 0);
  };

  auto compute = [&](int cur) {
#pragma unroll
    for (int ks = 0; ks < 2; ++ks) {
      const int bg = ks * 4 + quad;  // 16B-block 0..7 inside BK=64
      s16x8 af[2], bfr[4];
#pragma unroll
      for (int mt = 0; mt < 2; ++mt) {
        const int m = wm * 32 + mt * 16 + l16;
        af[mt] = *(const s16x8_a*)&Alds[cur][m * 64 + ((bg ^ (m & 7)) << 3)];
      }
#pragma unroll
      for (int nt = 0; nt < 4; ++nt) {
        const int o = wn * 64 + nt * 16 + l16;
        bfr[nt] = *(const s16x8_a*)&Blds[cur][o * 64 + ((bg ^ (o & 7)) << 3)];
      }
#pragma unroll
      for (int mt = 0; mt < 2; ++mt)
#pragma unroll
        for (int nt = 0; nt < 4; ++nt)
          acc[mt][nt] = __builtin_amdgcn_mfma_f32_16x16x32_bf16(af[mt], bfr[nt],
                                                                acc[mt][nt], 0, 0, 0);
    }
  };

  const int NKT = KDIM / 64;   // 54
  stage(0, 0);
  stage(1, 64);

  for (int kt = 0; kt < NKT; ++kt) {
    // my tile-kt loads arrived (6 newest = tile kt+1 keep flying)
    if (kt < NKT - 1) asm volatile("s_waitcnt vmcnt(6)" ::: "memory");
    else              asm volatile("s_waitcnt vmcnt(0)" ::: "memory");
    asm volatile("s_waitcnt lgkmcnt(0)" ::: "memory");   // free here
    __builtin_amdgcn_s_barrier();        // tile kt in for ALL; compute(kt-1)
    asm volatile("" ::: "memory");       //   done for ALL -> buf[(kt-1)%3] free
    if (kt + 2 < NKT) stage((kt + 2) % 3, (kt + 2) * 64);
    compute(kt % 3);
  }

#pragma unroll
  for (int mt = 0; mt < 2; ++mt) {
    const int growb = nbase + (int)rowbase + wm * 32 + mt * 16 + quad * 4;
#pragma unroll
    for (int r = 0; r < 4; ++r) {
      const int grow = growb + r;
      if (grow < N) {
#pragma unroll
        for (int nt = 0; nt < 4; ++nt) {
          const int o = wn * 64 + nt * 16 + l16;
          out[(size_t)grow * 128 + o] = acc[mt][nt][r];
        }
      }
    }
  }
}

// --------------------------------------------------------------------------
extern "C" void kernel_launch(void* const* d_in, const int* in_sizes, int n_in,
                              void* d_out, int out_size, void* d_ws, size_t ws_size,
                              hipStream_t stream) {
  const float* feat = (const float*)d_in[0];   // [N,128] fp32
  const float* sel  = (const float*)d_in[1];   // [N,32,27] fp32
  const float* wgt  = (const float*)d_in[2];   // [27,128*128] fp32
  const int*   nidx = (const int*)d_in[3];     // [N,32] int32
  float* out = (float*)d_out;                  // [N,128,1] fp32
  const int N = in_sizes[0] / N_CHI;           // 50000

  unsigned short* Wt = (unsigned short*)d_ws;        // 128*3456 bf16 = 884736 B
  const size_t WT_ELEMS = (size_t)128 * KDIM;
  unsigned short* FB = Wt + WT_ELEMS;                // N*128 bf16 = 12.8 MB
  const size_t FB_ELEMS = (size_t)N * N_CHI;
  unsigned short* T = FB + FB_ELEMS;                 // chunked [NC,3456] bf16

  // fused prep: featbf (total4 threads/4) + wconv transpose
  const int total4 = (int)(FB_ELEMS / 4);
  const int fb_blks = (total4 + 255) / 256;          // 6250
  const int wt_blks = (N_SP * 128 * 128) / 256;      // 1728
  prep_kernel<<<dim3((unsigned)(fb_blks + wt_blks)), 256, 0, stream>>>(
      feat, FB, total4, wgt, Wt, fb_blks);

  // chunk size: T-chunk must be L3-resident (256 MB). NC=25088 -> 173 MB.
  const size_t used = (WT_ELEMS + FB_ELEMS) * 2;
  const size_t bytes_for_T = (ws_size > used) ? (ws_size - used) : 0;
  long cap_rows = (long)(bytes_for_T / ((size_t)KDIM * 2));
  long NC = (cap_rows / 128) * 128;
  if (NC > 25088) NC = 25088;
  const long Nfull = (((long)N + 127) / 128) * 128;
  if (NC > Nfull) NC = Nfull;
  if (NC <= 0) return;  // workspace too small (not expected)

  for (long nb = 0; nb < N; nb += NC) {
    long rows = (long)N - nb;
    if (rows > NC) rows = NC;
    const long rows64 = ((rows + 63) / 64) * 64;      // <= NC (NC mult of 128)
    phase1_kernel<<<dim3((unsigned)((rows + 3) / 4)), 256, 0, stream>>>(
        FB, sel, nidx, T, (int)nb, (int)(nb + rows));
    phase2_kernel<<<dim3((unsigned)(rows64 / 64)), 256, 0, stream>>>(
        T, Wt, out, (int)nb, N);
  }
}

// Round 7
// 504.089 us; speedup vs baseline: 1.0160x; 1.0160x over previous
//
#include <hip/hip_runtime.h>

// ---------------------------------------------------------------------------
// CConv: out[n,o] = sum_{m,s,i} sel[n,m,s] * W[s,o,i] * feat[idx[n,m], i]
// Prep:   fused kernel: feat->bf16 AND W->Wt bf16 (k-contiguous), one launch.
// Phase 1: t[n,s,i] = sum_m sel*pf per-n via 32x32x16 MFMA (R5 version:
//          full tbuf, contiguous full-row T store; 167us full-N, 46% HBM).
// Phase 2: out = T x Wt^T, 16x16x32 bf16, BK=64.
//          R7: 64x128 tile + 2-buffer counted-vmcnt pipeline, 48KB LDS ->
//          3 blocks/CU, full-N grid 782 -> 3.05 resident/CU.
//          Session matrix: 2buf@1.5blk=113us(R1/R3), 3buf@1blk=186(R4),
//          1buf@3blk=137(R5) -> this is the untested pipeline+TLP cell.
// R6 lessons: harness re-poisons full ws (~100us fill, fixed tax); chunking
//          for L3 residency = null (T writes traverse HBM regardless) and
//          halved p2's grid -> de-chunked.
// ---------------------------------------------------------------------------

#define N_CHI 128
#define N_SP  27
#define N_M   32
#define KDIM  (N_SP * N_CHI)      // 3456
#define SEL_STRIDE (N_M * N_SP)   // 864

typedef short s16x8 __attribute__((ext_vector_type(8)));
typedef s16x8 __attribute__((may_alias)) s16x8_a;
typedef unsigned short u16x8 __attribute__((ext_vector_type(8)));
typedef u16x8 __attribute__((may_alias)) u16x8_a;
typedef unsigned int u32x2 __attribute__((ext_vector_type(2)));
typedef u32x2 __attribute__((may_alias)) u32x2_a;
typedef float f32x4 __attribute__((ext_vector_type(4)));
typedef f32x4 __attribute__((may_alias)) f32x4_a;
typedef float f32x16 __attribute__((ext_vector_type(16)));

typedef __attribute__((address_space(3))) unsigned int as3_u32;
typedef __attribute__((address_space(1))) const unsigned int as1_u32;

static __device__ __forceinline__ unsigned short f2bf(float f) {
  unsigned int u = __float_as_uint(f);
  u += 0x7FFFu + ((u >> 16) & 1u);   // round-to-nearest-even (inputs finite)
  return (unsigned short)(u >> 16);
}

// --------------------------------------------------------------------------
// Prep (fused): blocks [0, FB_BLKS): feat fp32 -> bf16 (4 elems/thread).
//               blocks [FB_BLKS, FB_BLKS+WT_BLKS): W -> Wt bf16 transpose.
// --------------------------------------------------------------------------
__global__ __launch_bounds__(256) void prep_kernel(
    const float* __restrict__ feat, unsigned short* __restrict__ fb, int total4,
    const float* __restrict__ w, unsigned short* __restrict__ Wt, int fb_blks) {
  const int b = (int)blockIdx.x;
  if (b < fb_blks) {
    const int i = b * 256 + (int)threadIdx.x;
    if (i >= total4) return;
    f32x4 v = *(const f32x4_a*)&feat[(size_t)i * 4];
    u32x2 o;
    o[0] = (unsigned int)f2bf(v[0]) | ((unsigned int)f2bf(v[1]) << 16);
    o[1] = (unsigned int)f2bf(v[2]) | ((unsigned int)f2bf(v[3]) << 16);
    *(u32x2_a*)&fb[(size_t)i * 4] = o;
  } else {
    // e enumerates (s*128+o)*128+i linearly -> coalesced read of w
    const int e = (b - fb_blks) * 256 + (int)threadIdx.x;   // < 27*128*128
    const int i = e & 127;
    const int so = e >> 7;
    const int o = so & 127;
    const int s = so >> 7;
    Wt[((size_t)o * N_SP + s) * N_CHI + i] = f2bf(w[e]);
  }
}

// --------------------------------------------------------------------------
// Kernel 1: per-n  t^T[i][s] = pf^T(128x32m) x sel(32m x 32s)  via 32x32x16.
// acc -> per-wave LDS tbuf (8B-granule XOR swizzle) -> 7 coalesced b128
// stores of the FULL contiguous T row (no write amplification).
// --------------------------------------------------------------------------
__global__ __launch_bounds__(256, 5) void phase1_kernel(
    const unsigned short* __restrict__ featbf, const float* __restrict__ sel,
    const int* __restrict__ nidx, unsigned short* __restrict__ T,
    int nbase, int nend) {
  __shared__ __align__(16) unsigned short tbuf[4][N_SP * 128]; // 27648 B
  const int wave = threadIdx.x >> 6;
  const int lane = threadIdx.x & 63;
  const int n = nbase + (int)blockIdx.x * 4 + wave;
  if (n >= nend) return;                 // wave-private LDS: no barriers needed
  unsigned short* tb = tbuf[wave];
  const int q = lane >> 5;     // 0..1  (K-half)
  const int col = lane & 31;   // A-row (i_local) == B-col (s)
  const bool sv = (col < N_SP);

  // B fragments: direct coalesced loads (no LDS staging)
  const float* selp = sel + (size_t)n * SEL_STRIDE;
  s16x8 bf0, bf1;
#pragma unroll
  for (int j = 0; j < 8; ++j) {
    const int m0 = q * 8 + j;
    float v0 = sv ? selp[m0 * N_SP + col] : 0.0f;
    float v1 = sv ? selp[(16 + m0) * N_SP + col] : 0.0f;
    bf0[j] = (short)f2bf(v0);
    bf1[j] = (short)f2bf(v1);
  }

  // neighbor element offsets for this lane's k positions: m = ks*16 + q*8 + j
  const int* ip = nidx + (size_t)n * N_M;
  int offe[16];
#pragma unroll
  for (int ks = 0; ks < 2; ++ks)
#pragma unroll
    for (int j = 0; j < 8; ++j)
      offe[ks * 8 + j] = ip[ks * 16 + q * 8 + j] * N_CHI;

#pragma unroll
  for (int ti = 0; ti < 4; ++ti) {
    const int icol = ti * 32 + col;
    s16x8 af0, af1;
#pragma unroll
    for (int j = 0; j < 8; ++j) {
      af0[j] = (short)featbf[offe[j] + icol];
      af1[j] = (short)featbf[offe[8 + j] + icol];
    }
    f32x16 acc = {0.f, 0.f, 0.f, 0.f, 0.f, 0.f, 0.f, 0.f,
                  0.f, 0.f, 0.f, 0.f, 0.f, 0.f, 0.f, 0.f};
    acc = __builtin_amdgcn_mfma_f32_32x32x16_bf16(af0, bf0, acc, 0, 0, 0);
    acc = __builtin_amdgcn_mfma_f32_32x32x16_bf16(af1, bf1, acc, 0, 0, 0);
    if (sv) {  // s = col; drop padding rows
#pragma unroll
      for (int g = 0; g < 4; ++g) {  // i = ti*32 + q*4 + g*8 + {0..3}
        const int sub = ti * 8 + g * 2 + q;                 // logical granule 0..31
        const int phys = col * 128 + (((sub ^ ((col & 7) << 2))) << 2);
        u32x2 pk;
        pk[0] = (unsigned int)f2bf(acc[4 * g + 0]) | ((unsigned int)f2bf(acc[4 * g + 1]) << 16);
        pk[1] = (unsigned int)f2bf(acc[4 * g + 2]) | ((unsigned int)f2bf(acc[4 * g + 3]) << 16);
        *(u32x2_a*)&tb[phys] = pk;
      }
    }
  }

  // coalesced store: 432 granule-pairs (16B each), 7 wave-iters, CONTIGUOUS row
  unsigned short* Tn = T + (size_t)(n - nbase) * KDIM;
#pragma unroll
  for (int it = 0; it < 7; ++it) {
    const int P = it * 64 + lane;      // pair id, 0..431
    if (P < 432) {
      const int c = P >> 4;            // col (s), 0..26
      const int sub = (P << 1) & 31;   // even logical granule
      const int phys = c * 128 + (((sub ^ ((c & 7) << 2))) << 2);  // 16B aligned
      *(u16x8_a*)&Tn[(size_t)P * 8] = *(const u16x8_a*)&tb[phys];
    }
  }
}

// --------------------------------------------------------------------------
// Kernel 2: out[64n x 128o] = T[64 x 3456] x Wt^T, 16x16x32 bf16, BK=64.
// global_load_lds staging, global-side XOR swizzle (LDS dest must be linear);
// frag ds_read_b128 conflict-free: phys 16B-block bp holds bg = bp ^ (row&7).
// R7 pipeline (R3 schedule, 6 loads/stage): 2 buffers, depth-2 prefetch:
//   iter kt: vmcnt(6) [tile kt in, kt+1 flying] -> barrier -> compute(kt&1)
//   -> lgkmcnt(0) -> barrier -> stage(kt+2 -> buf kt&1).
// 48 KB LDS -> 3 blocks/CU; grid 782 -> 3.05 resident blocks/CU (TLP).
// 4 waves: wave (wm=w&1: 32 rows, wn=w>>1: 64 cols) -> acc 2x4 C-tiles.
// --------------------------------------------------------------------------
__global__ __launch_bounds__(256) void phase2_kernel(
    const unsigned short* __restrict__ T, const unsigned short* __restrict__ Wt,
    float* __restrict__ out, int nbase, int N) {
  __shared__ __align__(16) unsigned short Alds[2][64 * 64];    // 16 KB
  __shared__ __align__(16) unsigned short Blds[2][128 * 64];   // 32 KB
  const int tid = threadIdx.x;
  const int lane = tid & 63;
  const int wbase = tid & ~63;          // wave*64 (uniform per wave)
  const int wave = tid >> 6;
  const int wm = wave & 1, wn = wave >> 1;
  const int quad = lane >> 4, l16 = lane & 15;
  const size_t rowbase = (size_t)blockIdx.x * 64;

  f32x4 acc[2][4];
#pragma unroll
  for (int a = 0; a < 2; ++a)
#pragma unroll
    for (int b = 0; b < 4; ++b) acc[a][b] = (f32x4){0.f, 0.f, 0.f, 0.f};

  // per-thread staging source addresses (slot = it*256 + tid -> row, 16B-block)
  const unsigned short* aga[2];   // A: 64 rows x 8 blocks = 512 slots
  const unsigned short* bga[4];   // B: 128 rows x 8 blocks = 1024 slots
#pragma unroll
  for (int it = 0; it < 2; ++it) {
    const int slot = it * 256 + tid;
    const int r = slot >> 3, bp = slot & 7;
    aga[it] = T + (rowbase + r) * KDIM + ((bp ^ (r & 7)) << 3);
  }
#pragma unroll
  for (int it = 0; it < 4; ++it) {
    const int slot = it * 256 + tid;
    const int r = slot >> 3, bp = slot & 7;
    bga[it] = Wt + (size_t)r * KDIM + ((bp ^ (r & 7)) << 3);
  }

  auto stage = [&](int buf, int k0) {
#pragma unroll
    for (int it = 0; it < 2; ++it)
      __builtin_amdgcn_global_load_lds(
          (as1_u32*)(const void*)(aga[it] + k0),
          (as3_u32*)(void*)&Alds[buf][(it * 256 + wbase) * 8], 16, 0, 0);
#pragma unroll
    for (int it = 0; it < 4; ++it)
      __builtin_amdgcn_global_load_lds(
          (as1_u32*)(const void*)(bga[it] + k0),
          (as3_u32*)(void*)&Blds[buf][(it * 256 + wbase) * 8], 16, 0, 0);
  };

  auto compute = [&](int cur) {
#pragma unroll
    for (int ks = 0; ks < 2; ++ks) {
      const int bg = ks * 4 + quad;  // 16B-block 0..7 inside BK=64
      s16x8 af[2], bfr[4];
#pragma unroll
      for (int mt = 0; mt < 2; ++mt) {
        const int m = wm * 32 + mt * 16 + l16;
        af[mt] = *(const s16x8_a*)&Alds[cur][m * 64 + ((bg ^ (m & 7)) << 3)];
      }
#pragma unroll
      for (int nt = 0; nt < 4; ++nt) {
        const int o = wn * 64 + nt * 16 + l16;
        bfr[nt] = *(const s16x8_a*)&Blds[cur][o * 64 + ((bg ^ (o & 7)) << 3)];
      }
#pragma unroll
      for (int mt = 0; mt < 2; ++mt)
#pragma unroll
        for (int nt = 0; nt < 4; ++nt)
          acc[mt][nt] = __builtin_amdgcn_mfma_f32_16x16x32_bf16(af[mt], bfr[nt],
                                                                acc[mt][nt], 0, 0, 0);
    }
  };

  const int NKT = KDIM / 64;   // 54
  stage(0, 0);
  stage(1, 64);

  for (int kt = 0; kt < NKT; ++kt) {
    // my tile-kt loads arrived (6 newest = tile kt+1 keep flying)
    if (kt < NKT - 1) asm volatile("s_waitcnt vmcnt(6)" ::: "memory");
    else              asm volatile("s_waitcnt vmcnt(0)" ::: "memory");
    __builtin_amdgcn_s_barrier();        // everyone's tile-kt contributions in
    asm volatile("" ::: "memory");       // pin ds_reads below the barrier
    compute(kt & 1);
    if (kt + 2 < NKT) {
      // my ds_reads of buf[kt&1] retired before anyone overwrites it
      asm volatile("s_waitcnt lgkmcnt(0)" ::: "memory");
      __builtin_amdgcn_s_barrier();
      stage(kt & 1, (kt + 2) * 64);
    }
  }

#pragma unroll
  for (int mt = 0; mt < 2; ++mt) {
    const int growb = nbase + (int)rowbase + wm * 32 + mt * 16 + quad * 4;
#pragma unroll
    for (int r = 0; r < 4; ++r) {
      const int grow = growb + r;
      if (grow < N) {
#pragma unroll
        for (int nt = 0; nt < 4; ++nt) {
          const int o = wn * 64 + nt * 16 + l16;
          out[(size_t)grow * 128 + o] = acc[mt][nt][r];
        }
      }
    }
  }
}

// --------------------------------------------------------------------------
extern "C" void kernel_launch(void* const* d_in, const int* in_sizes, int n_in,
                              void* d_out, int out_size, void* d_ws, size_t ws_size,
                              hipStream_t stream) {
  const float* feat = (const float*)d_in[0];   // [N,128] fp32
  const float* sel  = (const float*)d_in[1];   // [N,32,27] fp32
  const float* wgt  = (const float*)d_in[2];   // [27,128*128] fp32
  const int*   nidx = (const int*)d_in[3];     // [N,32] int32
  float* out = (float*)d_out;                  // [N,128,1] fp32
  const int N = in_sizes[0] / N_CHI;           // 50000

  unsigned short* Wt = (unsigned short*)d_ws;        // 128*3456 bf16 = 884736 B
  const size_t WT_ELEMS = (size_t)128 * KDIM;
  unsigned short* FB = Wt + WT_ELEMS;                // N*128 bf16 = 12.8 MB
  const size_t FB_ELEMS = (size_t)N * N_CHI;
  unsigned short* T = FB + FB_ELEMS;                 // chunked [NC,3456] bf16

  // fused prep: featbf (total4 threads/4) + wconv transpose
  const int total4 = (int)(FB_ELEMS / 4);
  const int fb_blks = (total4 + 255) / 256;          // 6250
  const int wt_blks = (N_SP * 128 * 128) / 256;      // 1728
  prep_kernel<<<dim3((unsigned)(fb_blks + wt_blks)), 256, 0, stream>>>(
      feat, FB, total4, wgt, Wt, fb_blks);

  const size_t used = (WT_ELEMS + FB_ELEMS) * 2;
  const size_t bytes_for_T = (ws_size > used) ? (ws_size - used) : 0;
  long cap_rows = (long)(bytes_for_T / ((size_t)KDIM * 2));
  long NC = (cap_rows / 128) * 128;
  const long Nfull = (((long)N + 127) / 128) * 128;
  if (NC > Nfull) NC = Nfull;
  if (NC <= 0) return;  // workspace too small (not expected)

  for (long nb = 0; nb < N; nb += NC) {
    long rows = (long)N - nb;
    if (rows > NC) rows = NC;
    const long rows64 = ((rows + 63) / 64) * 64;      // <= NC (NC mult of 128)
    phase1_kernel<<<dim3((unsigned)((rows + 3) / 4)), 256, 0, stream>>>(
        FB, sel, nidx, T, (int)nb, (int)(nb + rows));
    phase2_kernel<<<dim3((unsigned)(rows64 / 64)), 256, 0, stream>>>(
        T, Wt, out, (int)nb, N);
  }
}

// Round 8
// 474.793 us; speedup vs baseline: 1.0786x; 1.0617x over previous
//
#include <hip/hip_runtime.h>

// ---------------------------------------------------------------------------
// CConv: out[n,o] = sum_{m,s,i} sel[n,m,s] * W[s,o,i] * feat[idx[n,m], i]
// Prep:   fused kernel: feat->bf16 AND W->Wt bf16 (k-contiguous), one launch.
// Phase 1: t[n,s,i] = sum_m sel*pf per-n via 32x32x16 MFMA.
//          R8: gather restructure. Old: 64x 2B scalar global gathers per n
//          (128B/instr, latency chains -> VALUBusy 27%, 57% of BW floor).
//          New: 8x coalesced global_load_lds DMAs (1KB each; per-lane source
//          address carries the gather) stage the 32 rows in LDS; A-frags
//          built with ds_read_u16 (4-way alias, ~free). The 8KB/wave stage
//          buffer is TIME-SHARED: after frags live in VGPRs it becomes the
//          output-transpose tbuf (6.9KB) -> LDS/block stays 32KB, 5 blk/CU.
// Phase 2: out = T x Wt^T (R7: 64x128 tile, 2-buf counted-vmcnt, 3 blk/CU).
//          Schedule matrix complete: all variants ~130-150us band -> frozen.
// Fixed tax (R6): harness re-poisons ws (~100us fill) inside timed window.
// ---------------------------------------------------------------------------

#define N_CHI 128
#define N_SP  27
#define N_M   32
#define KDIM  (N_SP * N_CHI)      // 3456
#define SEL_STRIDE (N_M * N_SP)   // 864

typedef short s16x8 __attribute__((ext_vector_type(8)));
typedef s16x8 __attribute__((may_alias)) s16x8_a;
typedef unsigned short u16x8 __attribute__((ext_vector_type(8)));
typedef u16x8 __attribute__((may_alias)) u16x8_a;
typedef unsigned int u32x2 __attribute__((ext_vector_type(2)));
typedef u32x2 __attribute__((may_alias)) u32x2_a;
typedef float f32x4 __attribute__((ext_vector_type(4)));
typedef f32x4 __attribute__((may_alias)) f32x4_a;
typedef float f32x16 __attribute__((ext_vector_type(16)));

typedef __attribute__((address_space(3))) unsigned int as3_u32;
typedef __attribute__((address_space(1))) const unsigned int as1_u32;

static __device__ __forceinline__ unsigned short f2bf(float f) {
  unsigned int u = __float_as_uint(f);
  u += 0x7FFFu + ((u >> 16) & 1u);   // round-to-nearest-even (inputs finite)
  return (unsigned short)(u >> 16);
}

// --------------------------------------------------------------------------
// Prep (fused): blocks [0, FB_BLKS): feat fp32 -> bf16 (4 elems/thread).
//               blocks [FB_BLKS, FB_BLKS+WT_BLKS): W -> Wt bf16 transpose.
// --------------------------------------------------------------------------
__global__ __launch_bounds__(256) void prep_kernel(
    const float* __restrict__ feat, unsigned short* __restrict__ fb, int total4,
    const float* __restrict__ w, unsigned short* __restrict__ Wt, int fb_blks) {
  const int b = (int)blockIdx.x;
  if (b < fb_blks) {
    const int i = b * 256 + (int)threadIdx.x;
    if (i >= total4) return;
    f32x4 v = *(const f32x4_a*)&feat[(size_t)i * 4];
    u32x2 o;
    o[0] = (unsigned int)f2bf(v[0]) | ((unsigned int)f2bf(v[1]) << 16);
    o[1] = (unsigned int)f2bf(v[2]) | ((unsigned int)f2bf(v[3]) << 16);
    *(u32x2_a*)&fb[(size_t)i * 4] = o;
  } else {
    // e enumerates (s*128+o)*128+i linearly -> coalesced read of w
    const int e = (b - fb_blks) * 256 + (int)threadIdx.x;   // < 27*128*128
    const int i = e & 127;
    const int so = e >> 7;
    const int o = so & 127;
    const int s = so >> 7;
    Wt[((size_t)o * N_SP + s) * N_CHI + i] = f2bf(w[e]);
  }
}

// --------------------------------------------------------------------------
// Kernel 1: per-n  t^T[i][s] = pf^T(128x32m) x sel(32m x 32s)  via 32x32x16.
// R8 flow (wave-private, no barriers):
//   1) 8x global_load_lds: stage 32 gathered feat rows [m][128i] into sbuf
//   2) sel -> bf0/bf1 (direct, unchanged)
//   3) vmcnt(0); build ALL 8 A-frags via ds_read_u16 into VGPRs
//   4) per ti: 2 MFMA -> acc -> pack -> write into sbuf REUSED as tbuf
//      ([27 s][128i], 8B-granule XOR swizzle phys = sub ^ ((s&7)<<2))
//   5) 7 coalesced b128 reads + contiguous full-row T stores
// --------------------------------------------------------------------------
__global__ __launch_bounds__(256, 5) void phase1_kernel(
    const unsigned short* __restrict__ featbf, const float* __restrict__ sel,
    const int* __restrict__ nidx, unsigned short* __restrict__ T,
    int nbase, int nend) {
  __shared__ __align__(16) unsigned short sbuf[4][4096];   // 8 KB/wave, 32 KB
  const int wave = threadIdx.x >> 6;
  const int lane = threadIdx.x & 63;
  const int n = nbase + (int)blockIdx.x * 4 + wave;
  if (n >= nend) return;                 // wave-private LDS: no barriers needed
  unsigned short* sb = sbuf[wave];
  const int q = lane >> 5;     // 0..1  (K-half)
  const int col = lane & 31;   // A-row (i_local) == B-col (s)
  const bool sv = (col < N_SP);
  const int grp = lane >> 4;   // 0..3  (16-lane staging group)
  const int l16 = lane & 15;

  // 1) stage 32 gathered rows -> sbuf[m*128 + i], 8 coalesced 1KB DMAs
  const int* ip = nidx + (size_t)n * N_M;
#pragma unroll
  for (int it = 0; it < 8; ++it) {
    const int ridx = ip[it * 4 + grp];   // row for this 16-lane group
    __builtin_amdgcn_global_load_lds(
        (as1_u32*)(const void*)(featbf + (size_t)ridx * N_CHI + l16 * 8),
        (as3_u32*)(void*)&sb[it * 512], 16, 0, 0);
  }

  // 2) sel B fragments: direct coalesced loads (unchanged)
  const float* selp = sel + (size_t)n * SEL_STRIDE;
  s16x8 bf0, bf1;
#pragma unroll
  for (int j = 0; j < 8; ++j) {
    const int m0 = q * 8 + j;
    float v0 = sv ? selp[m0 * N_SP + col] : 0.0f;
    float v1 = sv ? selp[(16 + m0) * N_SP + col] : 0.0f;
    bf0[j] = (short)f2bf(v0);
    bf1[j] = (short)f2bf(v1);
  }

  // 3) staging DMA complete, then build all 8 A-frags from LDS
  asm volatile("s_waitcnt vmcnt(0)" ::: "memory");
  __builtin_amdgcn_sched_barrier(0);
  s16x8 af[4][2];
#pragma unroll
  for (int ti = 0; ti < 4; ++ti) {
    const int icol = ti * 32 + col;
#pragma unroll
    for (int j = 0; j < 8; ++j) {
      af[ti][0][j] = (short)sb[(q * 8 + j) * N_CHI + icol];        // m = q*8+j
      af[ti][1][j] = (short)sb[(16 + q * 8 + j) * N_CHI + icol];   // m = 16+q*8+j
    }
  }
  // all frag reads retired before sbuf is reused as tbuf (DS pipe is in-order
  // per wave; fence keeps the compiler from proving-disjoint and reordering)
  asm volatile("s_waitcnt lgkmcnt(0)" ::: "memory");
  __builtin_amdgcn_sched_barrier(0);

  // 4) MFMA per ti, writeback into sbuf-as-tbuf with XOR swizzle
#pragma unroll
  for (int ti = 0; ti < 4; ++ti) {
    f32x16 acc = {0.f, 0.f, 0.f, 0.f, 0.f, 0.f, 0.f, 0.f,
                  0.f, 0.f, 0.f, 0.f, 0.f, 0.f, 0.f, 0.f};
    acc = __builtin_amdgcn_mfma_f32_32x32x16_bf16(af[ti][0], bf0, acc, 0, 0, 0);
    acc = __builtin_amdgcn_mfma_f32_32x32x16_bf16(af[ti][1], bf1, acc, 0, 0, 0);
    if (sv) {  // s = col; drop padding rows
#pragma unroll
      for (int g = 0; g < 4; ++g) {  // i = ti*32 + q*4 + g*8 + {0..3}
        const int sub = ti * 8 + g * 2 + q;                 // logical granule 0..31
        const int phys = col * 128 + (((sub ^ ((col & 7) << 2))) << 2);
        u32x2 pk;
        pk[0] = (unsigned int)f2bf(acc[4 * g + 0]) | ((unsigned int)f2bf(acc[4 * g + 1]) << 16);
        pk[1] = (unsigned int)f2bf(acc[4 * g + 2]) | ((unsigned int)f2bf(acc[4 * g + 3]) << 16);
        *(u32x2_a*)&sb[phys] = pk;
      }
    }
  }

  // 5) coalesced store: 432 granule-pairs (16B each), 7 wave-iters, CONTIG row
  unsigned short* Tn = T + (size_t)(n - nbase) * KDIM;
#pragma unroll
  for (int it = 0; it < 7; ++it) {
    const int P = it * 64 + lane;      // pair id, 0..431
    if (P < 432) {
      const int c = P >> 4;            // col (s), 0..26
      const int sub = (P << 1) & 31;   // even logical granule
      const int phys = c * 128 + (((sub ^ ((c & 7) << 2))) << 2);  // 16B aligned
      *(u16x8_a*)&Tn[(size_t)P * 8] = *(const u16x8_a*)&sb[phys];
    }
  }
}

// --------------------------------------------------------------------------
// Kernel 2: out[64n x 128o] = T[64 x 3456] x Wt^T, 16x16x32 bf16, BK=64.
// global_load_lds staging, global-side XOR swizzle (LDS dest must be linear);
// frag ds_read_b128 conflict-free: phys 16B-block bp holds bg = bp ^ (row&7).
// Pipeline (frozen): 2 buffers, depth-2 prefetch, counted vmcnt(6).
// 48 KB LDS -> 3 blocks/CU; grid 782 -> ~3 resident blocks/CU (TLP).
// --------------------------------------------------------------------------
__global__ __launch_bounds__(256) void phase2_kernel(
    const unsigned short* __restrict__ T, const unsigned short* __restrict__ Wt,
    float* __restrict__ out, int nbase, int N) {
  __shared__ __align__(16) unsigned short Alds[2][64 * 64];    // 16 KB
  __shared__ __align__(16) unsigned short Blds[2][128 * 64];   // 32 KB
  const int tid = threadIdx.x;
  const int lane = tid & 63;
  const int wbase = tid & ~63;          // wave*64 (uniform per wave)
  const int wave = tid >> 6;
  const int wm = wave & 1, wn = wave >> 1;
  const int quad = lane >> 4, l16 = lane & 15;
  const size_t rowbase = (size_t)blockIdx.x * 64;

  f32x4 acc[2][4];
#pragma unroll
  for (int a = 0; a < 2; ++a)
#pragma unroll
    for (int b = 0; b < 4; ++b) acc[a][b] = (f32x4){0.f, 0.f, 0.f, 0.f};

  // per-thread staging source addresses (slot = it*256 + tid -> row, 16B-block)
  const unsigned short* aga[2];   // A: 64 rows x 8 blocks = 512 slots
  const unsigned short* bga[4];   // B: 128 rows x 8 blocks = 1024 slots
#pragma unroll
  for (int it = 0; it < 2; ++it) {
    const int slot = it * 256 + tid;
    const int r = slot >> 3, bp = slot & 7;
    aga[it] = T + (rowbase + r) * KDIM + ((bp ^ (r & 7)) << 3);
  }
#pragma unroll
  for (int it = 0; it < 4; ++it) {
    const int slot = it * 256 + tid;
    const int r = slot >> 3, bp = slot & 7;
    bga[it] = Wt + (size_t)r * KDIM + ((bp ^ (r & 7)) << 3);
  }

  auto stage = [&](int buf, int k0) {
#pragma unroll
    for (int it = 0; it < 2; ++it)
      __builtin_amdgcn_global_load_lds(
          (as1_u32*)(const void*)(aga[it] + k0),
          (as3_u32*)(void*)&Alds[buf][(it * 256 + wbase) * 8], 16, 0, 0);
#pragma unroll
    for (int it = 0; it < 4; ++it)
      __builtin_amdgcn_global_load_lds(
          (as1_u32*)(const void*)(bga[it] + k0),
          (as3_u32*)(void*)&Blds[buf][(it * 256 + wbase) * 8], 16, 0, 0);
  };

  auto compute = [&](int cur) {
#pragma unroll
    for (int ks = 0; ks < 2; ++ks) {
      const int bg = ks * 4 + quad;  // 16B-block 0..7 inside BK=64
      s16x8 af[2], bfr[4];
#pragma unroll
      for (int mt = 0; mt < 2; ++mt) {
        const int m = wm * 32 + mt * 16 + l16;
        af[mt] = *(const s16x8_a*)&Alds[cur][m * 64 + ((bg ^ (m & 7)) << 3)];
      }
#pragma unroll
      for (int nt = 0; nt < 4; ++nt) {
        const int o = wn * 64 + nt * 16 + l16;
        bfr[nt] = *(const s16x8_a*)&Blds[cur][o * 64 + ((bg ^ (o & 7)) << 3)];
      }
#pragma unroll
      for (int mt = 0; mt < 2; ++mt)
#pragma unroll
        for (int nt = 0; nt < 4; ++nt)
          acc[mt][nt] = __builtin_amdgcn_mfma_f32_16x16x32_bf16(af[mt], bfr[nt],
                                                                acc[mt][nt], 0, 0, 0);
    }
  };

  const int NKT = KDIM / 64;   // 54
  stage(0, 0);
  stage(1, 64);

  for (int kt = 0; kt < NKT; ++kt) {
    // my tile-kt loads arrived (6 newest = tile kt+1 keep flying)
    if (kt < NKT - 1) asm volatile("s_waitcnt vmcnt(6)" ::: "memory");
    else              asm volatile("s_waitcnt vmcnt(0)" ::: "memory");
    __builtin_amdgcn_s_barrier();        // everyone's tile-kt contributions in
    asm volatile("" ::: "memory");       // pin ds_reads below the barrier
    compute(kt & 1);
    if (kt + 2 < NKT) {
      // my ds_reads of buf[kt&1] retired before anyone overwrites it
      asm volatile("s_waitcnt lgkmcnt(0)" ::: "memory");
      __builtin_amdgcn_s_barrier();
      stage(kt & 1, (kt + 2) * 64);
    }
  }

#pragma unroll
  for (int mt = 0; mt < 2; ++mt) {
    const int growb = nbase + (int)rowbase + wm * 32 + mt * 16 + quad * 4;
#pragma unroll
    for (int r = 0; r < 4; ++r) {
      const int grow = growb + r;
      if (grow < N) {
#pragma unroll
        for (int nt = 0; nt < 4; ++nt) {
          const int o = wn * 64 + nt * 16 + l16;
          out[(size_t)grow * 128 + o] = acc[mt][nt][r];
        }
      }
    }
  }
}

// --------------------------------------------------------------------------
extern "C" void kernel_launch(void* const* d_in, const int* in_sizes, int n_in,
                              void* d_out, int out_size, void* d_ws, size_t ws_size,
                              hipStream_t stream) {
  const float* feat = (const float*)d_in[0];   // [N,128] fp32
  const float* sel  = (const float*)d_in[1];   // [N,32,27] fp32
  const float* wgt  = (const float*)d_in[2];   // [27,128*128] fp32
  const int*   nidx = (const int*)d_in[3];     // [N,32] int32
  float* out = (float*)d_out;                  // [N,128,1] fp32
  const int N = in_sizes[0] / N_CHI;           // 50000

  unsigned short* Wt = (unsigned short*)d_ws;        // 128*3456 bf16 = 884736 B
  const size_t WT_ELEMS = (size_t)128 * KDIM;
  unsigned short* FB = Wt + WT_ELEMS;                // N*128 bf16 = 12.8 MB
  const size_t FB_ELEMS = (size_t)N * N_CHI;
  unsigned short* T = FB + FB_ELEMS;                 // chunked [NC,3456] bf16

  // fused prep: featbf (total4 threads/4) + wconv transpose
  const int total4 = (int)(FB_ELEMS / 4);
  const int fb_blks = (total4 + 255) / 256;          // 6250
  const int wt_blks = (N_SP * 128 * 128) / 256;      // 1728
  prep_kernel<<<dim3((unsigned)(fb_blks + wt_blks)), 256, 0, stream>>>(
      feat, FB, total4, wgt, Wt, fb_blks);

  const size_t used = (WT_ELEMS + FB_ELEMS) * 2;
  const size_t bytes_for_T = (ws_size > used) ? (ws_size - used) : 0;
  long cap_rows = (long)(bytes_for_T / ((size_t)KDIM * 2));
  long NC = (cap_rows / 128) * 128;
  const long Nfull = (((long)N + 127) / 128) * 128;
  if (NC > Nfull) NC = Nfull;
  if (NC <= 0) return;  // workspace too small (not expected)

  for (long nb = 0; nb < N; nb += NC) {
    long rows = (long)N - nb;
    if (rows > NC) rows = NC;
    const long rows64 = ((rows + 63) / 64) * 64;      // <= NC (NC mult of 128)
    phase1_kernel<<<dim3((unsigned)((rows + 3) / 4)), 256, 0, stream>>>(
        FB, sel, nidx, T, (int)nb, (int)(nb + rows));
    phase2_kernel<<<dim3((unsigned)(rows64 / 64)), 256, 0, stream>>>(
        T, Wt, out, (int)nb, N);
  }
}